// Round 3
// baseline (39154.538 us; speedup 1.0000x reference)
//
#include <hip/hip_runtime.h>
#include <cmath>

constexpr int B = 256, T = 1024, D = 128, H = 256, NC = 10;
constexpr int K  = D + H;                  // 384 rows: [x(128) | h(256)]
constexpr int NG = 16;                     // batch groups, 16 batches each
constexpr int NS = 16;                     // unit slices, 16 units -> 64 cols each
constexpr int SLICE_COLS = 64;
constexpr int WSLICE = K * SLICE_COLS;     // 24576 floats per slice (96 KB)

// ws layout (floats):
//   Wpack [NS][K][64]        @ 0          unit-interleaved col = u*4+gate
//   hbuf  [2][NG][H][16]     @ HB_OFF     per-group h tiles, [unit][batch]
//   ctr   [NG] (as int)      @ CTR_OFF    monotonic group barrier counters
constexpr size_t WP_OFF  = 0;
constexpr size_t HB_OFF  = (size_t)NS * WSLICE;             // 393216
constexpr size_t CTR_OFF = HB_OFF + 2ull * NG * H * 16;     // 524288
// total ~2.1 MB of ws

// LDS: W[384][64]=96KB + A[384][16]=24KB + Z[8][4][64][4]=32KB = 155648 B
constexpr unsigned SMEM_BYTES = (K * SLICE_COLS + K * 16 + 8 * 4 * 64 * 4) * 4;

__device__ __forceinline__ float fast_sig(float x) { return 1.f / (1.f + __expf(-x)); }
__device__ __forceinline__ float fast_tanh(float x) {
  float ax = fabsf(x);
  float e = __expf(2.f * ax);              // overflow -> inf -> r -> 1, safe
  float r = 1.f - 2.f / (e + 1.f);
  return copysignf(r, x);
}

// Repack: Wpack[s][k][u*4+g'] ; j_global = s*16+u ; k<128 from w*x else w*h.
// Also zero the group barrier counters.
__global__ void setup_kernel(const float* __restrict__ wgx, const float* __restrict__ wgh,
                             const float* __restrict__ wix, const float* __restrict__ wih,
                             const float* __restrict__ wfx, const float* __restrict__ wfh,
                             const float* __restrict__ wox, const float* __restrict__ woh,
                             float* __restrict__ ws) {
  int idx = blockIdx.x * blockDim.x + threadIdx.x;   // 0 .. NS*WSLICE-1
  if (idx < NG) ((int*)(ws + CTR_OFF))[idx] = 0;
  int s = idx / WSLICE;
  int r = idx - s * WSLICE;
  int k = r >> 6;
  int c = r & 63;
  int u = c >> 2, gp = c & 3;
  int j = s * 16 + u;
  const float* wxs[4] = {wgx, wix, wfx, wox};
  const float* whs[4] = {wgh, wih, wfh, woh};
  float v = (k < D) ? wxs[gp][k * H + j] : whs[gp][(k - D) * H + j];
  ws[WP_OFF + idx] = v;
}

// Persistent block (g,s): batches [16g,16g+16), units [16s,16s+16) (64 cols).
// Weights live in LDS for the whole run. One group barrier (16 blocks) per step.
// blockIdx = s*16+g -> group g's blocks all have bid%8 == g%8 (same XCD if %8 mapping).
__launch_bounds__(512, 1)
__global__ void lstm_persist(const float* __restrict__ x,
                             const float* __restrict__ bgp, const float* __restrict__ bip,
                             const float* __restrict__ bfp, const float* __restrict__ bop,
                             float* __restrict__ ws) {
  extern __shared__ float smem[];
  float* Wl = smem;                      // [384][64]
  float* Al = smem + K * 64;             // [384][16]  rows<128: x_t, rows>=128: h_{t-1}
  float* Zl = smem + K * 64 + K * 16;    // [8 ks][4 ci][64 lane][4 e]

  float* hb  = ws + HB_OFF;
  int*   ctr = (int*)(ws + CTR_OFF);

  const int tid = threadIdx.x;
  const int s = blockIdx.x >> 4;
  const int g = blockIdx.x & 15;

  // ---- stage weight slice into LDS (once) ----
  const float* wsrc = ws + WP_OFF + (size_t)s * WSLICE;
  #pragma unroll
  for (int p = 0; p < 12; ++p) {
    int f = p * 2048 + tid * 4;
    *(float4*)(Wl + f) = *(const float4*)(wsrc + f);
  }
  // zero h region of A (4096 floats)
  *(float4*)(Al + D * 16 + tid * 4)        = make_float4(0.f, 0.f, 0.f, 0.f);
  *(float4*)(Al + D * 16 + 2048 + tid * 4) = make_float4(0.f, 0.f, 0.f, 0.f);

  // x gather role: thread -> (d = tid>>2, bq = tid&3); loads 4 batches' x[.][t][d]
  const int xd = tid >> 2, xbq = tid & 3;
  const float* xbase = x + (size_t)(g * 16 + xbq * 4) * T * D + xd;
  // stage x_0
  {
    float4 xv;
    xv.x = xbase[0 * (size_t)T * D];
    xv.y = xbase[1 * (size_t)T * D];
    xv.z = xbase[2 * (size_t)T * D];
    xv.w = xbase[3 * (size_t)T * D];
    *(float4*)(Al + xd * 16 + xbq * 4) = xv;
  }

  // k-loop roles
  const int ks = tid >> 6;               // wave id = k-slice (48 rows)
  const int local = tid & 63;
  const int cq = local >> 2, bq = local & 3;
  const float* wp = Wl + (ks * 48) * 64 + cq * 4;
  const float* ap = Al + (ks * 48) * 16 + bq * 4;
  float* zp = Zl + ((size_t)(ks * 4) * 64 + local) * 4;

  // epilogue role (tid<256): unit u = tid>>4, batch b = tid&15
  const int eu = tid >> 4, eb = tid & 15;
  const int ej = s * 16 + eu;
  float bgv = 0.f, biv = 0.f, bfv = 0.f, bov = 0.f;
  if (tid < 256) { bgv = bgp[ej]; biv = bip[ej]; bfv = bfp[ej]; bov = bop[ej]; }
  float cs = 0.f;
  float* hslot = hb + (size_t)g * 4096 + ej * 16 + eb;     // + parity*65536
  const float* hsrc_g = hb + (size_t)g * 4096;             // + parity*65536

  __syncthreads();   // W, A ready

  for (int t = 0; t < T; ++t) {
    // prefetch x_{t+1} (consumed at stage phase)
    const size_t tn = (size_t)((t + 1 < T) ? t + 1 : t) * D;
    float xn0 = xbase[0 * (size_t)T * D + tn];
    float xn1 = xbase[1 * (size_t)T * D + tn];
    float xn2 = xbase[2 * (size_t)T * D + tn];
    float xn3 = xbase[3 * (size_t)T * D + tn];

    // ---- k-loop: 48 rows x (4 cols x 4 batches) ----
    float acc[4][4];
    #pragma unroll
    for (int i = 0; i < 4; ++i)
      #pragma unroll
      for (int j = 0; j < 4; ++j) acc[i][j] = 0.f;

    #pragma unroll 8
    for (int k = 0; k < 48; ++k) {
      const float4 wv = *(const float4*)(wp + k * 64);
      const float4 av = *(const float4*)(ap + k * 16);
      acc[0][0] = fmaf(wv.x, av.x, acc[0][0]); acc[0][1] = fmaf(wv.x, av.y, acc[0][1]);
      acc[0][2] = fmaf(wv.x, av.z, acc[0][2]); acc[0][3] = fmaf(wv.x, av.w, acc[0][3]);
      acc[1][0] = fmaf(wv.y, av.x, acc[1][0]); acc[1][1] = fmaf(wv.y, av.y, acc[1][1]);
      acc[1][2] = fmaf(wv.y, av.z, acc[1][2]); acc[1][3] = fmaf(wv.y, av.w, acc[1][3]);
      acc[2][0] = fmaf(wv.z, av.x, acc[2][0]); acc[2][1] = fmaf(wv.z, av.y, acc[2][1]);
      acc[2][2] = fmaf(wv.z, av.z, acc[2][2]); acc[2][3] = fmaf(wv.z, av.w, acc[2][3]);
      acc[3][0] = fmaf(wv.w, av.x, acc[3][0]); acc[3][1] = fmaf(wv.w, av.y, acc[3][1]);
      acc[3][2] = fmaf(wv.w, av.z, acc[3][2]); acc[3][3] = fmaf(wv.w, av.w, acc[3][3]);
    }
    // Z write: lane-contiguous 16B per instr (2-way, free)
    #pragma unroll
    for (int ci = 0; ci < 4; ++ci)
      *(float4*)(zp + (size_t)ci * 64 * 4) =
        make_float4(acc[ci][0], acc[ci][1], acc[ci][2], acc[ci][3]);

    __syncthreads();   // Z complete, A reads done

    // ---- epilogue: reduce 8 k-slices, gates, c in regs, h tile -> global ----
    if (tid < 256) {
      float z0 = 0.f, z1 = 0.f, z2 = 0.f, z3 = 0.f;
      const int lslot = eu * 4 + (eb >> 2);
      const int e = eb & 3;
      #pragma unroll
      for (int kk = 0; kk < 8; ++kk) {
        const float* zr = Zl + ((size_t)(kk * 4) * 64 + lslot) * 4 + e;
        z0 += zr[0 * 64 * 4];
        z1 += zr[1 * 64 * 4];
        z2 += zr[2 * 64 * 4];
        z3 += zr[3 * 64 * 4];
      }
      float gv = fast_tanh(z0 + bgv);
      float iv = fast_sig (z1 + biv);
      float fv = fast_sig (z2 + bfv);
      float ov = fast_sig (z3 + bov);
      cs = gv * iv + cs * fv;
      float hn = fast_tanh(cs) * ov;
      __hip_atomic_store(hslot + (size_t)(t & 1) * 65536, hn,
                         __ATOMIC_RELAXED, __HIP_MEMORY_SCOPE_AGENT);
    }
    __threadfence();
    __syncthreads();   // all h stores drained before signal; Z reads done

    // ---- group barrier (16 blocks), monotonic counter ----
    if (tid == 0) {
      __hip_atomic_fetch_add(ctr + g, 1, __ATOMIC_RELEASE, __HIP_MEMORY_SCOPE_AGENT);
      const int target = (t + 1) * NS;
      while (__hip_atomic_load(ctr + g, __ATOMIC_ACQUIRE, __HIP_MEMORY_SCOPE_AGENT) < target)
        __builtin_amdgcn_s_sleep(2);
    }
    __syncthreads();

    // ---- stage h_t (all 256 units) and x_{t+1} into A ----
    {
      const float* hsrc = hsrc_g + (size_t)(t & 1) * 65536;
      #pragma unroll
      for (int p = 0; p < 2; ++p) {
        int f = p * 2048 + tid * 4;
        float4 hv;
        hv.x = __hip_atomic_load(hsrc + f + 0, __ATOMIC_RELAXED, __HIP_MEMORY_SCOPE_AGENT);
        hv.y = __hip_atomic_load(hsrc + f + 1, __ATOMIC_RELAXED, __HIP_MEMORY_SCOPE_AGENT);
        hv.z = __hip_atomic_load(hsrc + f + 2, __ATOMIC_RELAXED, __HIP_MEMORY_SCOPE_AGENT);
        hv.w = __hip_atomic_load(hsrc + f + 3, __ATOMIC_RELAXED, __HIP_MEMORY_SCOPE_AGENT);
        *(float4*)(Al + D * 16 + f) = hv;
      }
      *(float4*)(Al + xd * 16 + xbq * 4) = make_float4(xn0, xn1, xn2, xn3);
    }
    __syncthreads();   // A ready for next step
  }
}

// out[b][c] = sum_j h[j of b] * wph[j][c] + bp[c]; h at hb1[g=b>>4][j][b&15]
__global__ void proj_kernel(const float* __restrict__ hb1, const float* __restrict__ wph,
                            const float* __restrict__ bp, float* __restrict__ out) {
  int b = blockIdx.x;
  int j = threadIdx.x;
  float hv = hb1[(size_t)(b >> 4) * 4096 + j * 16 + (b & 15)];
  float p[NC];
  #pragma unroll
  for (int c = 0; c < NC; ++c) p[c] = hv * wph[j * NC + c];
  #pragma unroll
  for (int off = 32; off >= 1; off >>= 1)
    #pragma unroll
    for (int c = 0; c < NC; ++c) p[c] += __shfl_xor(p[c], off, 64);
  __shared__ float sred[NC];
  if (threadIdx.x < NC) sred[threadIdx.x] = 0.f;
  __syncthreads();
  if ((threadIdx.x & 63) == 0)
    for (int c = 0; c < NC; ++c) atomicAdd(&sred[c], p[c]);
  __syncthreads();
  if (j < NC) out[b * NC + j] = sred[j] + bp[j];
}

extern "C" void kernel_launch(void* const* d_in, const int* in_sizes, int n_in,
                              void* d_out, int out_size, void* d_ws, size_t ws_size,
                              hipStream_t stream) {
  const float* x   = (const float*)d_in[0];
  const float* wgx = (const float*)d_in[1];
  const float* wgh = (const float*)d_in[2];
  const float* bg  = (const float*)d_in[3];
  const float* wix = (const float*)d_in[4];
  const float* wih = (const float*)d_in[5];
  const float* bi  = (const float*)d_in[6];
  const float* wfx = (const float*)d_in[7];
  const float* wfh = (const float*)d_in[8];
  const float* bf  = (const float*)d_in[9];
  const float* wox = (const float*)d_in[10];
  const float* woh = (const float*)d_in[11];
  const float* bo  = (const float*)d_in[12];
  const float* wph = (const float*)d_in[13];
  const float* bp  = (const float*)d_in[14];
  float* out = (float*)d_out;
  float* ws  = (float*)d_ws;

  setup_kernel<<<(NS * WSLICE) / 256, 256, 0, stream>>>(wgx, wgh, wix, wih,
                                                        wfx, wfh, wox, woh, ws);

  static bool attr_set = false;
  if (!attr_set) {
    hipFuncSetAttribute((const void*)lstm_persist,
                        hipFuncAttributeMaxDynamicSharedMemorySize, SMEM_BYTES);
    attr_set = true;
  }
  void* args[] = {(void*)&x, (void*)&bg, (void*)&bi, (void*)&bf, (void*)&bo, (void*)&ws};
  hipError_t e = hipLaunchCooperativeKernel((const void*)lstm_persist, dim3(NS * NG),
                                            dim3(512), args, SMEM_BYTES, stream);
  if (e != hipSuccess)   // fallback: 256 blocks x 1/CU co-reside by construction
    lstm_persist<<<NS * NG, 512, SMEM_BYTES, stream>>>(x, bg, bi, bf, bo, ws);

  // final h parity: (T-1)&1 = 1
  proj_kernel<<<B, H, 0, stream>>>(ws + HB_OFF + 65536, wph, bp, out);
}

// Round 4
// 6443.703 us; speedup vs baseline: 6.0764x; 6.0764x over previous
//
#include <hip/hip_runtime.h>
#include <cmath>

constexpr int B = 256, T = 1024, D = 128, H = 256, NC = 10;
constexpr int K  = D + H;                  // 384 rows: [x(128) | h(256)]
constexpr int NG = 16;                     // batch groups (16 batches each)
constexpr int NS = 16;                     // unit slices (16 units -> 64 cols)

// ws: htag[2][NG][H*16] of uint64 @ 0   (1 MB)
//   slot = parity*NG*4096 + g*4096 + unit*16 + batch
//   word = (tag << 32) | float_bits(h);  tag of h_t is t.
constexpr size_t HS_PAR = (size_t)NG * H * 16;     // 65536 slots per parity

// LDS: W[384][64] 96KB + A[384][16] 24KB + Z[8][4][64][4] 32KB = 155648 B
constexpr unsigned SMEM_FLOATS = K * 64 + K * 16 + 8 * 4 * 64 * 4;
constexpr unsigned SMEM_BYTES  = SMEM_FLOATS * 4;

__device__ __forceinline__ float fast_sig(float x) { return 1.f / (1.f + __expf(-x)); }
__device__ __forceinline__ float fast_tanh(float x) {
  float ax = fabsf(x);
  float e = __expf(2.f * ax);              // overflow -> inf -> r -> 1, safe
  float r = 1.f - 2.f / (e + 1.f);
  return copysignf(r, x);
}

// Init tag buffer: parity 0 = (tag 0, h=0) == h_0 ; parity 1 = sentinel tag.
__global__ void setup_kernel(unsigned long long* __restrict__ hb) {
  size_t idx = (size_t)blockIdx.x * blockDim.x + threadIdx.x;   // 0 .. 131071
  hb[idx] = (idx < HS_PAR) ? 0ull : 0xFFFFFFFF00000000ull;
}

// 16 fma: acc[ci][bj] += WV[ci] * AV[bj]
#define FMA16T(WV, AV) { \
  acc[0][0]=fmaf((WV).x,(AV).x,acc[0][0]); acc[0][1]=fmaf((WV).x,(AV).y,acc[0][1]); \
  acc[0][2]=fmaf((WV).x,(AV).z,acc[0][2]); acc[0][3]=fmaf((WV).x,(AV).w,acc[0][3]); \
  acc[1][0]=fmaf((WV).y,(AV).x,acc[1][0]); acc[1][1]=fmaf((WV).y,(AV).y,acc[1][1]); \
  acc[1][2]=fmaf((WV).y,(AV).z,acc[1][2]); acc[1][3]=fmaf((WV).y,(AV).w,acc[1][3]); \
  acc[2][0]=fmaf((WV).z,(AV).x,acc[2][0]); acc[2][1]=fmaf((WV).z,(AV).y,acc[2][1]); \
  acc[2][2]=fmaf((WV).z,(AV).z,acc[2][2]); acc[2][3]=fmaf((WV).z,(AV).w,acc[2][3]); \
  acc[3][0]=fmaf((WV).w,(AV).x,acc[3][0]); acc[3][1]=fmaf((WV).w,(AV).y,acc[3][1]); \
  acc[3][2]=fmaf((WV).w,(AV).z,acc[3][2]); acc[3][3]=fmaf((WV).w,(AV).w,acc[3][3]); }

// Persistent block (g,s): batches [16g,16g+16), units [16s,16s+16) (64 packed cols).
// Weights in LDS for the whole run. Barrier-free tag-polled h exchange.
__launch_bounds__(512, 1)
__global__ void lstm_persist(const float* __restrict__ x,
                             const float* __restrict__ bgp, const float* __restrict__ bip,
                             const float* __restrict__ bfp, const float* __restrict__ bop,
                             const float* __restrict__ wgx, const float* __restrict__ wgh,
                             const float* __restrict__ wix, const float* __restrict__ wih,
                             const float* __restrict__ wfx, const float* __restrict__ wfh,
                             const float* __restrict__ wox, const float* __restrict__ woh,
                             float* __restrict__ ws) {
  extern __shared__ float smem[];
  float* Wl = smem;                      // [384][64]  col = u*4 + gate
  float* Al = smem + K * 64;             // [384][16]  rows<128: x_t, rows>=128: h_t
  float* Zl = smem + K * 64 + K * 16;    // [8 ks][4 ci][64 slot][4 e]

  unsigned long long* hb = (unsigned long long*)ws;

  const int tid = threadIdx.x;
  const int s = blockIdx.x >> 4;
  const int g = blockIdx.x & 15;

  // ---- one-time: weight slice -> LDS directly from inputs ----
  for (int idx = tid; idx < K * 64; idx += 512) {
    int k = idx >> 6, c = idx & 63, u = c >> 2, gp = c & 3;
    int j = s * 16 + u;
    const float* wxp = (gp == 0) ? wgx : (gp == 1) ? wix : (gp == 2) ? wfx : wox;
    const float* whp = (gp == 0) ? wgh : (gp == 1) ? wih : (gp == 2) ? wfh : woh;
    Wl[idx] = (k < D) ? wxp[k * H + j] : whp[(k - D) * H + j];
  }

  // x gather role: (xd, xbq) loads 4 batches' x[.][t][xd]
  const int xd = tid >> 2, xbq = tid & 3;
  const float* xbase = x + (size_t)(g * 16 + xbq * 4) * T * D + xd;
  {
    float4 xv;
    xv.x = xbase[0 * (size_t)T * D]; xv.y = xbase[1 * (size_t)T * D];
    xv.z = xbase[2 * (size_t)T * D]; xv.w = xbase[3 * (size_t)T * D];
    *(float4*)(Al + xd * 16 + xbq * 4) = xv;
  }

  // k-loop roles: wave ks owns x-rows [16ks,16ks+16) and h-rows [128+32ks, +32)
  const int ks = tid >> 6;
  const int local = tid & 63;
  const int cq = local >> 2, bq = local & 3;
  const float* wpx = Wl + (size_t)(ks * 16) * 64 + cq * 4;
  const float* apx = Al + (size_t)(ks * 16) * 16 + bq * 4;
  const float* wph_ = Wl + (size_t)(D + ks * 32) * 64 + cq * 4;
  const float* aph  = Al + (size_t)(D + ks * 32) * 16 + bq * 4;
  float* zp = Zl + ((size_t)(ks * 4) * 64 + local) * 4;

  // epilogue role (tid<256): unit eu, batch eb
  const int eu = tid >> 4, eb = tid & 15;
  const int ej = s * 16 + eu;
  float bgv = 0.f, biv = 0.f, bfv = 0.f, bov = 0.f;
  if (tid < 256) { bgv = bgp[ej]; biv = bip[ej]; bfv = bfp[ej]; bov = bop[ej]; }
  float cs = 0.f;
  unsigned long long* pslot = hb + (size_t)g * 4096 + (size_t)ej * 16 + eb;

  // poll role: this thread's 8 slots (unit tid>>1, batches (tid&1)*8..+8)
  const size_t pollofs = (size_t)g * 4096 + (size_t)tid * 8;
  float* arow = Al + (size_t)(128 + (tid >> 1)) * 16 + (tid & 1) * 8;

  __syncthreads();   // W, x_0 staged

  for (int t = 0; t < T; ++t) {
    // ---- issue first-attempt polls (h_t), hide under x-part ----
    const unsigned long long* psrc = hb + (size_t)(t & 1) * HS_PAR + pollofs;
    unsigned long long got[8];
    #pragma unroll
    for (int i = 0; i < 8; ++i)
      got[i] = __hip_atomic_load(psrc + i, __ATOMIC_RELAXED, __HIP_MEMORY_SCOPE_AGENT);

    // x_{t+1} prefetch
    const size_t tn = (size_t)((t + 1 < T) ? t + 1 : t) * D;
    float xn0 = xbase[0 * (size_t)T * D + tn];
    float xn1 = xbase[1 * (size_t)T * D + tn];
    float xn2 = xbase[2 * (size_t)T * D + tn];
    float xn3 = xbase[3 * (size_t)T * D + tn];

    float acc[4][4];
    #pragma unroll
    for (int i = 0; i < 4; ++i)
      #pragma unroll
      for (int j = 0; j < 4; ++j) acc[i][j] = 0.f;

    // ---- x-part (rows 0..127): no h dependency ----
    #pragma unroll
    for (int k = 0; k < 16; ++k) {
      const float4 wv = *(const float4*)(wpx + (size_t)k * 64);
      const float4 av = *(const float4*)(apx + (size_t)k * 16);
      FMA16T(wv, av);
    }

    // ---- verify/retry polls; stage h_t into Al ----
    {
      const unsigned expt = (unsigned)t;
      while (true) {
        bool ok = true;
        #pragma unroll
        for (int i = 0; i < 8; ++i) {
          if ((unsigned)(got[i] >> 32) != expt) {
            got[i] = __hip_atomic_load(psrc + i, __ATOMIC_RELAXED, __HIP_MEMORY_SCOPE_AGENT);
            if ((unsigned)(got[i] >> 32) != expt) ok = false;
          }
        }
        if (ok) break;
        __builtin_amdgcn_s_sleep(1);
      }
      float4 h0, h1;
      h0.x = __uint_as_float((unsigned)got[0]); h0.y = __uint_as_float((unsigned)got[1]);
      h0.z = __uint_as_float((unsigned)got[2]); h0.w = __uint_as_float((unsigned)got[3]);
      h1.x = __uint_as_float((unsigned)got[4]); h1.y = __uint_as_float((unsigned)got[5]);
      h1.z = __uint_as_float((unsigned)got[6]); h1.w = __uint_as_float((unsigned)got[7]);
      *(float4*)arow       = h0;
      *(float4*)(arow + 4) = h1;
    }
    __syncthreads();   // h_t staged in Al

    // ---- h-part (rows 128..383) ----
    #pragma unroll 8
    for (int k = 0; k < 32; ++k) {
      const float4 wv = *(const float4*)(wph_ + (size_t)k * 64);
      const float4 av = *(const float4*)(aph  + (size_t)k * 16);
      FMA16T(wv, av);
    }
    #pragma unroll
    for (int ci = 0; ci < 4; ++ci)
      *(float4*)(zp + (size_t)ci * 64 * 4) =
        make_float4(acc[ci][0], acc[ci][1], acc[ci][2], acc[ci][3]);

    __syncthreads();   // Z complete

    // ---- epilogue: reduce, gates, publish tagged h_{t+1} ----
    if (tid < 256) {
      float z0 = 0.f, z1 = 0.f, z2 = 0.f, z3 = 0.f;
      const int lslot = eu * 4 + (eb >> 2);
      const int e = eb & 3;
      #pragma unroll
      for (int kk = 0; kk < 8; ++kk) {
        const float* zr = Zl + ((size_t)(kk * 4) * 64 + lslot) * 4 + e;
        z0 += zr[0 * 256];
        z1 += zr[1 * 256];
        z2 += zr[2 * 256];
        z3 += zr[3 * 256];
      }
      float gv = fast_tanh(z0 + bgv);
      float iv = fast_sig (z1 + biv);
      float fv = fast_sig (z2 + bfv);
      float ov = fast_sig (z3 + bov);
      cs = gv * iv + cs * fv;
      float hn = fast_tanh(cs) * ov;
      unsigned long long pv =
        ((unsigned long long)(unsigned)(t + 1) << 32) |
        (unsigned long long)__float_as_uint(hn);
      __hip_atomic_store(pslot + (size_t)((t + 1) & 1) * HS_PAR, pv,
                         __ATOMIC_RELAXED, __HIP_MEMORY_SCOPE_AGENT);
    }
    // stage x_{t+1} (x-part reads of step t finished before the Z barrier)
    *(float4*)(Al + xd * 16 + xbq * 4) = make_float4(xn0, xn1, xn2, xn3);

    __syncthreads();   // epilogue reads of Z done; x staged
  }
}

// out[b][c] = sum_j h_T[j][b] * wph[j][c] + bp[c]
// h_T: parity (T&1)=0 buffer, value = lo32 of tag word.
__global__ void proj_kernel(const unsigned long long* __restrict__ hb,
                            const float* __restrict__ wph,
                            const float* __restrict__ bp, float* __restrict__ out) {
  int b = blockIdx.x;
  int j = threadIdx.x;
  unsigned long long wv = hb[(size_t)(b >> 4) * 4096 + (size_t)j * 16 + (b & 15)];
  float hv = __uint_as_float((unsigned)wv);
  float p[NC];
  #pragma unroll
  for (int c = 0; c < NC; ++c) p[c] = hv * wph[j * NC + c];
  #pragma unroll
  for (int off = 32; off >= 1; off >>= 1)
    #pragma unroll
    for (int c = 0; c < NC; ++c) p[c] += __shfl_xor(p[c], off, 64);
  __shared__ float sred[NC];
  if (threadIdx.x < NC) sred[threadIdx.x] = 0.f;
  __syncthreads();
  if ((threadIdx.x & 63) == 0)
    for (int c = 0; c < NC; ++c) atomicAdd(&sred[c], p[c]);
  __syncthreads();
  if (j < NC) out[b * NC + j] = sred[j] + bp[j];
}

extern "C" void kernel_launch(void* const* d_in, const int* in_sizes, int n_in,
                              void* d_out, int out_size, void* d_ws, size_t ws_size,
                              hipStream_t stream) {
  const float* x   = (const float*)d_in[0];
  const float* wgx = (const float*)d_in[1];
  const float* wgh = (const float*)d_in[2];
  const float* bg  = (const float*)d_in[3];
  const float* wix = (const float*)d_in[4];
  const float* wih = (const float*)d_in[5];
  const float* bi  = (const float*)d_in[6];
  const float* wfx = (const float*)d_in[7];
  const float* wfh = (const float*)d_in[8];
  const float* bf  = (const float*)d_in[9];
  const float* wox = (const float*)d_in[10];
  const float* woh = (const float*)d_in[11];
  const float* bo  = (const float*)d_in[12];
  const float* wph = (const float*)d_in[13];
  const float* bp  = (const float*)d_in[14];
  float* out = (float*)d_out;
  float* ws  = (float*)d_ws;
  unsigned long long* hb = (unsigned long long*)ws;

  setup_kernel<<<(int)(2 * HS_PAR / 256), 256, 0, stream>>>(hb);

  static bool attr_set = false;
  if (!attr_set) {
    hipFuncSetAttribute((const void*)lstm_persist,
                        hipFuncAttributeMaxDynamicSharedMemorySize, SMEM_BYTES);
    attr_set = true;
  }
  void* args[] = {(void*)&x, (void*)&bg, (void*)&bi, (void*)&bf, (void*)&bo,
                  (void*)&wgx, (void*)&wgh, (void*)&wix, (void*)&wih,
                  (void*)&wfx, (void*)&wfh, (void*)&wox, (void*)&woh, (void*)&ws};
  hipError_t e = hipLaunchCooperativeKernel((const void*)lstm_persist,
                                            dim3(NS * NG), dim3(512), args,
                                            SMEM_BYTES, stream);
  if (e != hipSuccess)   // 256 blocks x 1/CU on 256 CUs co-reside by construction
    lstm_persist<<<NS * NG, 512, SMEM_BYTES, stream>>>(x, bg, bi, bf, bo,
                                                       wgx, wgh, wix, wih,
                                                       wfx, wfh, wox, woh, ws);

  proj_kernel<<<B, H, 0, stream>>>(hb, wph, bp, out);
}